// Round 1
// baseline (6347.559 us; speedup 1.0000x reference)
//
#include <hip/hip_runtime.h>
#include <cstdint>

// ---------------------------------------------------------------------------
// DGDN forward (B=4096). Outputs (f32, concat): x_rec[4096,1,28,28],
// mean[4096,80,16], log_var[4096,80,16], eta[4096,30,7,7,9].
// RNG: JAX threefry2x32, jax_threefry_partitionable=True reconstruction:
//   split  = foldlike:  key_i = tf(key, (0,i)) full pair
//   bits32 = o0 ^ o1 of tf(key, (0,flat_index))
// ---------------------------------------------------------------------------

#define OFF_MEAN 3211264
#define OFF_LV   8454144
#define OFF_ETA  13697024

// ------------------------- threefry2x32 (constexpr) ------------------------
constexpr uint64_t ctf(uint32_t k0, uint32_t k1, uint32_t x0, uint32_t x1) {
  uint32_t ks0 = k0, ks1 = k1, ks2 = k0 ^ k1 ^ 0x1BD11BDAu;
  const int rotA[4] = {13, 15, 26, 6};
  const int rotB[4] = {17, 29, 16, 24};
  x0 += ks0; x1 += ks1;
  for (int g = 0; g < 5; ++g) {
    for (int i = 0; i < 4; ++i) {
      int r = (g & 1) ? rotB[i] : rotA[i];
      x0 += x1;
      x1 = (uint32_t)((x1 << r) | (x1 >> (32 - r)));
      x1 ^= x0;
    }
    uint32_t ka = (g + 1) % 3 == 0 ? ks0 : ((g + 1) % 3 == 1 ? ks1 : ks2);
    uint32_t kb = (g + 2) % 3 == 0 ? ks0 : ((g + 2) % 3 == 1 ? ks1 : ks2);
    x0 += ka;
    x1 += kb + (uint32_t)(g + 1);
  }
  return ((uint64_t)x0 << 32) | (uint64_t)x1;
}

// jax.random.split(jax.random.key(42), 4)  [foldlike]
constexpr uint64_t KP_ = ctf(0u, 42u, 0u, 0u);  // k_pool
constexpr uint64_t KU_ = ctf(0u, 42u, 0u, 1u);  // k_unpool
constexpr uint64_t KC_ = ctf(0u, 42u, 0u, 2u);  // k_code
constexpr uint64_t KN_ = ctf(0u, 42u, 0u, 3u);  // k_noise
constexpr uint32_t KPOOL0 = (uint32_t)(KP_ >> 32), KPOOL1 = (uint32_t)KP_;
constexpr uint32_t KUNP0  = (uint32_t)(KU_ >> 32), KUNP1  = (uint32_t)KU_;
constexpr uint32_t KCODE0 = (uint32_t)(KC_ >> 32), KCODE1 = (uint32_t)KC_;
constexpr uint32_t KNOIS0 = (uint32_t)(KN_ >> 32), KNOIS1 = (uint32_t)KN_;

// ------------------------- device threefry + draws -------------------------
__device__ __forceinline__ uint2 tf_dev(uint32_t k0, uint32_t k1, uint32_t x0, uint32_t x1) {
  uint32_t ks2 = k0 ^ k1 ^ 0x1BD11BDAu;
  x0 += k0; x1 += k1;
#define TFR(r) { x0 += x1; x1 = (x1 << (r)) | (x1 >> (32 - (r))); x1 ^= x0; }
  TFR(13) TFR(15) TFR(26) TFR(6)
  x0 += k1;  x1 += ks2 + 1u;
  TFR(17) TFR(29) TFR(16) TFR(24)
  x0 += ks2; x1 += k0 + 2u;
  TFR(13) TFR(15) TFR(26) TFR(6)
  x0 += k0;  x1 += k1 + 3u;
  TFR(17) TFR(29) TFR(16) TFR(24)
  x0 += k1;  x1 += ks2 + 4u;
  TFR(13) TFR(15) TFR(26) TFR(6)
  x0 += ks2; x1 += k0 + 5u;
#undef TFR
  return make_uint2(x0, x1);
}

__device__ __forceinline__ uint32_t rbits32(uint32_t k0, uint32_t k1, uint32_t idx) {
  uint2 r = tf_dev(k0, k1, 0u, idx);
  return r.x ^ r.y;  // partitionable 32-bit combine
}

__device__ __forceinline__ float u01_from_bits(uint32_t bits) {
  return __uint_as_float((bits >> 9) | 0x3F800000u) - 1.0f;
}

// gumbel(key)[idx] = -log(-log(uniform(tiny, 1)))
__device__ __forceinline__ float gumbel_draw(uint32_t k0, uint32_t k1, uint32_t idx) {
  float u01 = u01_from_bits(rbits32(k0, k1, idx));
  float u = fmaxf(__fadd_rn(u01, 1.17549435e-38f), 1.17549435e-38f);
  return -logf(-logf(u));
}

// XLA f32 erf_inv (Giles), separate mul/add like the CPU reference
__device__ __forceinline__ float erfinv_xla(float x) {
  float t = __fmul_rn(x, x);
  float w = -log1pf(-t);
  float p;
  if (w < 5.0f) {
    w = __fadd_rn(w, -2.5f);
    p = 2.81022636e-08f;
    p = __fadd_rn(__fmul_rn(p, w), 3.43273939e-07f);
    p = __fadd_rn(__fmul_rn(p, w), -3.5233877e-06f);
    p = __fadd_rn(__fmul_rn(p, w), -4.39150654e-06f);
    p = __fadd_rn(__fmul_rn(p, w), 0.00021858087f);
    p = __fadd_rn(__fmul_rn(p, w), -0.00125372503f);
    p = __fadd_rn(__fmul_rn(p, w), -0.00417768164f);
    p = __fadd_rn(__fmul_rn(p, w), 0.246640727f);
    p = __fadd_rn(__fmul_rn(p, w), 1.50140941f);
  } else {
    w = __fadd_rn(sqrtf(w), -3.0f);
    p = -0.000200214257f;
    p = __fadd_rn(__fmul_rn(p, w), 0.000100950558f);
    p = __fadd_rn(__fmul_rn(p, w), 0.00134934322f);
    p = __fadd_rn(__fmul_rn(p, w), -0.00367342844f);
    p = __fadd_rn(__fmul_rn(p, w), 0.00573950773f);
    p = __fadd_rn(__fmul_rn(p, w), -0.0076224613f);
    p = __fadd_rn(__fmul_rn(p, w), 0.00943887047f);
    p = __fadd_rn(__fmul_rn(p, w), 1.00167406f);
    p = __fadd_rn(__fmul_rn(p, w), 2.83297682f);
  }
  return __fmul_rn(p, x);
}

// normal(key)[idx] = sqrt(2) * erfinv(uniform(nextafter(-1,0), 1))
__device__ __forceinline__ float normal_draw(uint32_t k0, uint32_t k1, uint32_t idx) {
  float u01 = u01_from_bits(rbits32(k0, k1, idx));
  float u = fmaxf(__fadd_rn(__fmul_rn(u01, 2.0f), -0.99999994f), -0.99999994f);
  return __fmul_rn(1.41421356237309515f, erfinv_xla(u));
}

// XLA/Eigen f32 tanh rational approximation (matches CPU reference tanh)
__device__ __forceinline__ float tanh_xla(float x) {
  float ax = fabsf(x);
  float xc = fmaxf(fminf(x, 7.90531110763549805f), -7.90531110763549805f);
  float x2 = __fmul_rn(xc, xc);
  float p = __fmaf_rn(x2, -2.76076847742355e-16f, 2.00018790482477e-13f);
  p = __fmaf_rn(x2, p, -8.60467152213735e-11f);
  p = __fmaf_rn(x2, p, 5.12229709037114e-08f);
  p = __fmaf_rn(x2, p, 1.48572235717979e-05f);
  p = __fmaf_rn(x2, p, 6.37261928875436e-04f);
  p = __fmaf_rn(x2, p, 4.89352455891786e-03f);
  p = __fmul_rn(xc, p);
  float q = __fmaf_rn(x2, 1.19825839466702e-06f, 1.18534705686654e-04f);
  q = __fmaf_rn(x2, q, 2.26843463243900e-03f);
  q = __fmaf_rn(x2, q, 4.89352518554385e-03f);
  return (ax < 0.0004f) ? x : __fdiv_rn(p, q);
}

// ---------------------------------------------------------------------------
// Encoder: conv1 -> pool MLPs -> eta/zeta/pooled -> conv2 -> code MLPs -> s
// One block per batch element b.
// ---------------------------------------------------------------------------
__global__ __launch_bounds__(256) void k_enc(
    const float* __restrict__ x, const float* __restrict__ enc1_w,
    const float* __restrict__ pw1, const float* __restrict__ pw2,
    const float* __restrict__ enc2_w, const float* __restrict__ h_w,
    const float* __restrict__ h_b, const float* __restrict__ mean_w,
    const float* __restrict__ mean_b, const float* __restrict__ lv_w,
    const float* __restrict__ lv_b,
    float* __restrict__ o_mean, float* __restrict__ o_lv, float* __restrict__ o_eta,
    float* __restrict__ ws_s, unsigned char* __restrict__ ws_z) {
  __shared__ float lds[10240];   // phase A: xs|w1s|pw ; phase B: wch|c2s|hs
  __shared__ float pooled[1470];
  const int b = blockIdx.x, tid = threadIdx.x;

  // ---- phase A: conv1 + stochastic pooling ----
  float* xs  = lds;          // 784
  float* w1s = lds + 784;    // 1920
  float* pp1 = lds + 2704;   // 81
  float* pp2 = lds + 2785;   // 81
  for (int i = tid; i < 784; i += 256) xs[i] = x[(size_t)b * 784 + i];
  for (int i = tid; i < 1920; i += 256) w1s[i] = enc1_w[i];
  if (tid < 81) { pp1[tid] = pw1[tid]; pp2[tid] = pw2[tid]; }
  __syncthreads();

  for (int idx = tid; idx < 1470; idx += 256) {
    int c = idx / 49, cell = idx - c * 49;
    int n = cell / 7, m = cell - n * 7;
    int yb = n * 3, xb = m * 3;
    float tile[9];
#pragma unroll
    for (int i = 0; i < 9; ++i) tile[i] = 0.f;
    const float* wc = &w1s[c * 64];
#pragma unroll
    for (int r = 0; r < 10; ++r) {
      float xr[10];
#pragma unroll
      for (int i = 0; i < 10; ++i) xr[i] = xs[(yb + r) * 28 + xb + i];
#pragma unroll
      for (int p = 0; p < 3; ++p) {
        int dy = r - p;
        if (dy >= 0 && dy < 8) {
#pragma unroll
          for (int dx = 0; dx < 8; ++dx) {
            float w = wc[dy * 8 + dx];
#pragma unroll
            for (int q = 0; q < 3; ++q) tile[p * 3 + q] += xr[q + dx] * w;
          }
        }
      }
    }
    // pooling MLPs
    float h1v[9];
#pragma unroll
    for (int o = 0; o < 9; ++o) {
      float a = 0.f;
#pragma unroll
      for (int t = 0; t < 9; ++t) a += tile[t] * pp1[o * 9 + t];
      h1v[o] = tanh_xla(a);
    }
    float lg[9], mx = -3.4e38f;
#pragma unroll
    for (int o = 0; o < 9; ++o) {
      float a = 0.f;
#pragma unroll
      for (int t = 0; t < 9; ++t) a += h1v[t] * pp2[o * 9 + t];
      lg[o] = a;
      mx = fmaxf(mx, a);
    }
    float ev[9], ssum = 0.f;
#pragma unroll
    for (int o = 0; o < 9; ++o) { ev[o] = expf(__fadd_rn(lg[o], -mx)); ssum += ev[o]; }
    float leta[9];
    size_t ebase = ((size_t)(b * 30 + c) * 49 + cell) * 9;
#pragma unroll
    for (int o = 0; o < 9; ++o) {
      float e = __fdiv_rn(ev[o], ssum);
      o_eta[ebase + o] = e;
      leta[o] = logf(e);
    }
    // zeta (pool pick) and zeta2 (unpool slot)
    uint32_t fb = (uint32_t)ebase;
    float best1 = -3.4e38f, best2 = -3.4e38f, pooledv = 0.f;
    int z2 = 0;
#pragma unroll
    for (int t = 0; t < 9; ++t) {
      float v1 = __fadd_rn(leta[t], gumbel_draw(KPOOL0, KPOOL1, fb + t));
      bool t1 = v1 > best1; best1 = t1 ? v1 : best1; pooledv = t1 ? tile[t] : pooledv;
      float v2 = __fadd_rn(leta[t], gumbel_draw(KUNP0, KUNP1, fb + t));
      bool t2 = v2 > best2; best2 = t2 ? v2 : best2; z2 = t2 ? t : z2;
    }
    pooled[idx] = pooledv;
    ws_z[(size_t)b * 1470 + idx] = (unsigned char)z2;
  }

  // ---- phase B: conv2 (chunked weights) -> h -> mean/logvar -> s ----
  float* wch = lds;          // 7680
  float* c2s = lds + 7680;   // 1280
  float* hs  = lds + 8960;   // 1280
  for (int ch = 0; ch < 5; ++ch) {
    __syncthreads();
    for (int i = tid; i < 7680; i += 256) wch[i] = enc2_w[ch * 7680 + i];
    __syncthreads();
    int k2l = tid >> 4, pos = tid & 15;
    int uy = pos >> 2, ux = pos & 3;
    float acc = 0.f;
    for (int c = 0; c < 30; ++c) {
      const float* pc = &pooled[c * 49];
      const float* wr = &wch[(k2l * 30 + c) * 16];
#pragma unroll
      for (int dy = 0; dy < 4; ++dy)
#pragma unroll
        for (int dx = 0; dx < 4; ++dx)
          acc += pc[(uy + dy) * 7 + ux + dx] * wr[dy * 4 + dx];
    }
    c2s[(ch * 16 + k2l) * 16 + pos] = acc;
  }
  __syncthreads();

#pragma unroll
  for (int j = 0; j < 5; ++j) {
    int it = tid + j * 256;          // (k2, o)
    int k2 = it >> 4;
    float d = 0.f;
    const float* wr = &h_w[(size_t)it * 16];
#pragma unroll
    for (int i = 0; i < 16; ++i) d += c2s[k2 * 16 + i] * wr[i];
    hs[it] = tanh_xla(__fadd_rn(d, h_b[it]));
  }
  __syncthreads();

#pragma unroll
  for (int j = 0; j < 5; ++j) {
    int it = tid + j * 256;
    int k2 = it >> 4;
    float dm = 0.f, dl = 0.f;
    const float* wm = &mean_w[(size_t)it * 16];
    const float* wl = &lv_w[(size_t)it * 16];
#pragma unroll
    for (int i = 0; i < 16; ++i) {
      float hv = hs[k2 * 16 + i];
      dm += hv * wm[i];
      dl += hv * wl[i];
    }
    float mean = __fadd_rn(dm, mean_b[it]);
    float lv = __fadd_rn(dl, lv_b[it]);
    size_t gi = (size_t)b * 1280 + it;
    o_mean[gi] = mean;
    o_lv[gi] = lv;
    float stdv = expf(__fmul_rn(0.5f, lv));
    float z = normal_draw(KCODE0, KCODE1, (uint32_t)(b * 1280 + it));
    ws_s[gi] = __fadd_rn(mean, __fmul_rn(stdv, z));
  }
}

// ---------------------------------------------------------------------------
// Decoder: convT(dec2) -> stochastic unpool -> convT(dec1) -> +diag noise
// One block per batch element b.
// ---------------------------------------------------------------------------
__global__ __launch_bounds__(256) void k_dec(
    const float* __restrict__ ws_s, const unsigned char* __restrict__ ws_z,
    const float* __restrict__ dec2_w, const float* __restrict__ dec1_w,
    const float* __restrict__ alpha, float* __restrict__ o_xrec) {
  __shared__ float sB[1280];
  __shared__ float wch[7680];
  __shared__ float s2v[1470];
  __shared__ float w1s[1920];
  __shared__ unsigned char zpy[1470];
  __shared__ unsigned char zpx[1470];
  const int b = blockIdx.x, tid = threadIdx.x;

  for (int i = tid; i < 1280; i += 256) sB[i] = ws_s[(size_t)b * 1280 + i];
  for (int i = tid; i < 1920; i += 256) w1s[i] = dec1_w[i];
  for (int i = tid; i < 1470; i += 256) {
    int cell = i % 49;
    int n = cell / 7, m = cell - n * 7;
    int z = ws_z[(size_t)b * 1470 + i];
    int p = z / 3, q = z - p * 3;
    zpy[i] = (unsigned char)(n * 3 + p);
    zpx[i] = (unsigned char)(m * 3 + q);
  }

  // s2 = convT(s, dec2_w): 1470 outputs, acc in registers, weights chunked
  float acc[6];
#pragma unroll
  for (int j = 0; j < 6; ++j) acc[j] = 0.f;
  for (int ch = 0; ch < 5; ++ch) {
    __syncthreads();
    for (int i = tid; i < 7680; i += 256) wch[i] = dec2_w[ch * 7680 + i];
    __syncthreads();
#pragma unroll
    for (int j = 0; j < 6; ++j) {
      int idx = tid + j * 256;
      if (idx < 1470) {
        int c = idx / 49, cell = idx - c * 49;
        int u = cell / 7, v = cell - u * 7;
        int iy0 = max(0, u - 3), iy1 = min(3, u);
        int ix0 = max(0, v - 3), ix1 = min(3, v);
        float a = acc[j];
        for (int k2l = 0; k2l < 16; ++k2l) {
          const float* sb = &sB[(ch * 16 + k2l) * 16];
          const float* wr = &wch[(k2l * 30 + c) * 16];
          for (int iy = iy0; iy <= iy1; ++iy)
            for (int ix = ix0; ix <= ix1; ++ix)
              a += sb[iy * 4 + ix] * wr[(u - iy) * 4 + (v - ix)];
        }
        acc[j] = a;
      }
    }
  }
  __syncthreads();
#pragma unroll
  for (int j = 0; j < 6; ++j) {
    int idx = tid + j * 256;
    if (idx < 1470) s2v[idx] = acc[j];
  }
  __syncthreads();

  // x_rec: gather over candidate tiles, add diagonal noise
  float inva = __fdiv_rn(1.0f, alpha[0]);
  for (int pix = tid; pix < 784; pix += 256) {
    int y = pix / 28, xx = pix - y * 28;
    float a = 0.f;
    int nlo = (y >= 9) ? (y - 7) / 3 : 0;
    int nhi = min(6, y / 3);
    int mlo = (xx >= 9) ? (xx - 7) / 3 : 0;
    int mhi = min(6, xx / 3);
    for (int c = 0; c < 30; ++c) {
      const float* wc1 = &w1s[c * 64];
      int cb = c * 49;
      for (int n = nlo; n <= nhi; ++n) {
        int rb = cb + n * 7;
        for (int m = mlo; m <= mhi; ++m) {
          int t = rb + m;
          int dy = y - (int)zpy[t];
          int dx = xx - (int)zpx[t];
          if ((unsigned)dy < 8u && (unsigned)dx < 8u)
            a += s2v[t] * wc1[dy * 8 + dx];
        }
      }
    }
    if (y == xx) {
      float z = normal_draw(KNOIS0, KNOIS1, (uint32_t)(b * 784 + pix));
      a = __fadd_rn(a, __fmul_rn(inva, z));
    }
    o_xrec[(size_t)b * 784 + pix] = a;
  }
}

// ---------------------------------------------------------------------------
extern "C" void kernel_launch(void* const* d_in, const int* in_sizes, int n_in,
                              void* d_out, int out_size, void* d_ws, size_t ws_size,
                              hipStream_t stream) {
  const float* x      = (const float*)d_in[0];
  const float* enc1_w = (const float*)d_in[1];
  const float* pw1    = (const float*)d_in[2];
  const float* pw2    = (const float*)d_in[3];
  const float* enc2_w = (const float*)d_in[4];
  const float* h_w    = (const float*)d_in[5];
  const float* h_b    = (const float*)d_in[6];
  const float* mean_w = (const float*)d_in[7];
  const float* mean_b = (const float*)d_in[8];
  const float* lv_w   = (const float*)d_in[9];
  const float* lv_b   = (const float*)d_in[10];
  const float* dec2_w = (const float*)d_in[11];
  const float* dec1_w = (const float*)d_in[12];
  const float* alpha  = (const float*)d_in[13];

  float* out = (float*)d_out;
  float* o_xrec = out;
  float* o_mean = out + OFF_MEAN;
  float* o_lv   = out + OFF_LV;
  float* o_eta  = out + OFF_ETA;

  float* ws_s = (float*)d_ws;                                   // 5,242,880 f32
  unsigned char* ws_z = (unsigned char*)d_ws + (size_t)5242880 * 4;  // 6,021,120 u8

  k_enc<<<dim3(4096), dim3(256), 0, stream>>>(
      x, enc1_w, pw1, pw2, enc2_w, h_w, h_b, mean_w, mean_b, lv_w, lv_b,
      o_mean, o_lv, o_eta, ws_s, ws_z);
  k_dec<<<dim3(4096), dim3(256), 0, stream>>>(
      ws_s, ws_z, dec2_w, dec1_w, alpha, o_xrec);
}

// Round 2
// 3798.669 us; speedup vs baseline: 1.6710x; 1.6710x over previous
//
#include <hip/hip_runtime.h>
#include <cstdint>

// ---------------------------------------------------------------------------
// DGDN forward (B=4096). Outputs (f32, concat): x_rec[4096,1,28,28],
// mean[4096,80,16], log_var[4096,80,16], eta[4096,30,7,7,9].
// RNG: JAX threefry2x32, jax_threefry_partitionable=True reconstruction.
// Decoder path: Wexp expansion + dense f32 GEMM + scatter-unpool (LDS atomics).
// ---------------------------------------------------------------------------

#define OFF_MEAN 3211264
#define OFF_LV   8454144
#define OFF_ETA  13697024

// ------------------------- threefry2x32 (constexpr) ------------------------
constexpr uint64_t ctf(uint32_t k0, uint32_t k1, uint32_t x0, uint32_t x1) {
  uint32_t ks0 = k0, ks1 = k1, ks2 = k0 ^ k1 ^ 0x1BD11BDAu;
  const int rotA[4] = {13, 15, 26, 6};
  const int rotB[4] = {17, 29, 16, 24};
  x0 += ks0; x1 += ks1;
  for (int g = 0; g < 5; ++g) {
    for (int i = 0; i < 4; ++i) {
      int r = (g & 1) ? rotB[i] : rotA[i];
      x0 += x1;
      x1 = (uint32_t)((x1 << r) | (x1 >> (32 - r)));
      x1 ^= x0;
    }
    uint32_t ka = (g + 1) % 3 == 0 ? ks0 : ((g + 1) % 3 == 1 ? ks1 : ks2);
    uint32_t kb = (g + 2) % 3 == 0 ? ks0 : ((g + 2) % 3 == 1 ? ks1 : ks2);
    x0 += ka;
    x1 += kb + (uint32_t)(g + 1);
  }
  return ((uint64_t)x0 << 32) | (uint64_t)x1;
}

constexpr uint64_t KP_ = ctf(0u, 42u, 0u, 0u);  // k_pool
constexpr uint64_t KU_ = ctf(0u, 42u, 0u, 1u);  // k_unpool
constexpr uint64_t KC_ = ctf(0u, 42u, 0u, 2u);  // k_code
constexpr uint64_t KN_ = ctf(0u, 42u, 0u, 3u);  // k_noise
constexpr uint32_t KPOOL0 = (uint32_t)(KP_ >> 32), KPOOL1 = (uint32_t)KP_;
constexpr uint32_t KUNP0  = (uint32_t)(KU_ >> 32), KUNP1  = (uint32_t)KU_;
constexpr uint32_t KCODE0 = (uint32_t)(KC_ >> 32), KCODE1 = (uint32_t)KC_;
constexpr uint32_t KNOIS0 = (uint32_t)(KN_ >> 32), KNOIS1 = (uint32_t)KN_;

// ------------------------- device threefry + draws -------------------------
__device__ __forceinline__ uint2 tf_dev(uint32_t k0, uint32_t k1, uint32_t x0, uint32_t x1) {
  uint32_t ks2 = k0 ^ k1 ^ 0x1BD11BDAu;
  x0 += k0; x1 += k1;
#define TFR(r) { x0 += x1; x1 = (x1 << (r)) | (x1 >> (32 - (r))); x1 ^= x0; }
  TFR(13) TFR(15) TFR(26) TFR(6)
  x0 += k1;  x1 += ks2 + 1u;
  TFR(17) TFR(29) TFR(16) TFR(24)
  x0 += ks2; x1 += k0 + 2u;
  TFR(13) TFR(15) TFR(26) TFR(6)
  x0 += k0;  x1 += k1 + 3u;
  TFR(17) TFR(29) TFR(16) TFR(24)
  x0 += k1;  x1 += ks2 + 4u;
  TFR(13) TFR(15) TFR(26) TFR(6)
  x0 += ks2; x1 += k0 + 5u;
#undef TFR
  return make_uint2(x0, x1);
}

__device__ __forceinline__ uint32_t rbits32(uint32_t k0, uint32_t k1, uint32_t idx) {
  uint2 r = tf_dev(k0, k1, 0u, idx);
  return r.x ^ r.y;
}

__device__ __forceinline__ float u01_from_bits(uint32_t bits) {
  return __uint_as_float((bits >> 9) | 0x3F800000u) - 1.0f;
}

__device__ __forceinline__ float gumbel_draw(uint32_t k0, uint32_t k1, uint32_t idx) {
  float u01 = u01_from_bits(rbits32(k0, k1, idx));
  float u = fmaxf(__fadd_rn(u01, 1.17549435e-38f), 1.17549435e-38f);
  return -logf(-logf(u));
}

__device__ __forceinline__ float erfinv_xla(float x) {
  float t = __fmul_rn(x, x);
  float w = -log1pf(-t);
  float p;
  if (w < 5.0f) {
    w = __fadd_rn(w, -2.5f);
    p = 2.81022636e-08f;
    p = __fadd_rn(__fmul_rn(p, w), 3.43273939e-07f);
    p = __fadd_rn(__fmul_rn(p, w), -3.5233877e-06f);
    p = __fadd_rn(__fmul_rn(p, w), -4.39150654e-06f);
    p = __fadd_rn(__fmul_rn(p, w), 0.00021858087f);
    p = __fadd_rn(__fmul_rn(p, w), -0.00125372503f);
    p = __fadd_rn(__fmul_rn(p, w), -0.00417768164f);
    p = __fadd_rn(__fmul_rn(p, w), 0.246640727f);
    p = __fadd_rn(__fmul_rn(p, w), 1.50140941f);
  } else {
    w = __fadd_rn(sqrtf(w), -3.0f);
    p = -0.000200214257f;
    p = __fadd_rn(__fmul_rn(p, w), 0.000100950558f);
    p = __fadd_rn(__fmul_rn(p, w), 0.00134934322f);
    p = __fadd_rn(__fmul_rn(p, w), -0.00367342844f);
    p = __fadd_rn(__fmul_rn(p, w), 0.00573950773f);
    p = __fadd_rn(__fmul_rn(p, w), -0.0076224613f);
    p = __fadd_rn(__fmul_rn(p, w), 0.00943887047f);
    p = __fadd_rn(__fmul_rn(p, w), 1.00167406f);
    p = __fadd_rn(__fmul_rn(p, w), 2.83297682f);
  }
  return __fmul_rn(p, x);
}

__device__ __forceinline__ float normal_draw(uint32_t k0, uint32_t k1, uint32_t idx) {
  float u01 = u01_from_bits(rbits32(k0, k1, idx));
  float u = fmaxf(__fadd_rn(__fmul_rn(u01, 2.0f), -0.99999994f), -0.99999994f);
  return __fmul_rn(1.41421356237309515f, erfinv_xla(u));
}

__device__ __forceinline__ float tanh_xla(float x) {
  float ax = fabsf(x);
  float xc = fmaxf(fminf(x, 7.90531110763549805f), -7.90531110763549805f);
  float x2 = __fmul_rn(xc, xc);
  float p = __fmaf_rn(x2, -2.76076847742355e-16f, 2.00018790482477e-13f);
  p = __fmaf_rn(x2, p, -8.60467152213735e-11f);
  p = __fmaf_rn(x2, p, 5.12229709037114e-08f);
  p = __fmaf_rn(x2, p, 1.48572235717979e-05f);
  p = __fmaf_rn(x2, p, 6.37261928875436e-04f);
  p = __fmaf_rn(x2, p, 4.89352455891786e-03f);
  p = __fmul_rn(xc, p);
  float q = __fmaf_rn(x2, 1.19825839466702e-06f, 1.18534705686654e-04f);
  q = __fmaf_rn(x2, q, 2.26843463243900e-03f);
  q = __fmaf_rn(x2, q, 4.89352518554385e-03f);
  return (ax < 0.0004f) ? x : __fdiv_rn(p, q);
}

// ---------------------------------------------------------------------------
// Encoder (UNCHANGED arithmetic — eta/zeta argmaxes depend on exact fp order).
// ---------------------------------------------------------------------------
__global__ __launch_bounds__(256) void k_enc(
    const float* __restrict__ x, const float* __restrict__ enc1_w,
    const float* __restrict__ pw1, const float* __restrict__ pw2,
    const float* __restrict__ enc2_w, const float* __restrict__ h_w,
    const float* __restrict__ h_b, const float* __restrict__ mean_w,
    const float* __restrict__ mean_b, const float* __restrict__ lv_w,
    const float* __restrict__ lv_b,
    float* __restrict__ o_mean, float* __restrict__ o_lv, float* __restrict__ o_eta,
    float* __restrict__ ws_s, unsigned char* __restrict__ ws_z) {
  __shared__ float lds[10240];
  __shared__ float pooled[1470];
  const int b = blockIdx.x, tid = threadIdx.x;

  float* xs  = lds;
  float* w1s = lds + 784;
  float* pp1 = lds + 2704;
  float* pp2 = lds + 2785;
  for (int i = tid; i < 784; i += 256) xs[i] = x[(size_t)b * 784 + i];
  for (int i = tid; i < 1920; i += 256) w1s[i] = enc1_w[i];
  if (tid < 81) { pp1[tid] = pw1[tid]; pp2[tid] = pw2[tid]; }
  __syncthreads();

  for (int idx = tid; idx < 1470; idx += 256) {
    int c = idx / 49, cell = idx - c * 49;
    int n = cell / 7, m = cell - n * 7;
    int yb = n * 3, xb = m * 3;
    float tile[9];
#pragma unroll
    for (int i = 0; i < 9; ++i) tile[i] = 0.f;
    const float* wc = &w1s[c * 64];
#pragma unroll
    for (int r = 0; r < 10; ++r) {
      float xr[10];
#pragma unroll
      for (int i = 0; i < 10; ++i) xr[i] = xs[(yb + r) * 28 + xb + i];
#pragma unroll
      for (int p = 0; p < 3; ++p) {
        int dy = r - p;
        if (dy >= 0 && dy < 8) {
#pragma unroll
          for (int dx = 0; dx < 8; ++dx) {
            float w = wc[dy * 8 + dx];
#pragma unroll
            for (int q = 0; q < 3; ++q) tile[p * 3 + q] += xr[q + dx] * w;
          }
        }
      }
    }
    float h1v[9];
#pragma unroll
    for (int o = 0; o < 9; ++o) {
      float a = 0.f;
#pragma unroll
      for (int t = 0; t < 9; ++t) a += tile[t] * pp1[o * 9 + t];
      h1v[o] = tanh_xla(a);
    }
    float lg[9], mx = -3.4e38f;
#pragma unroll
    for (int o = 0; o < 9; ++o) {
      float a = 0.f;
#pragma unroll
      for (int t = 0; t < 9; ++t) a += h1v[t] * pp2[o * 9 + t];
      lg[o] = a;
      mx = fmaxf(mx, a);
    }
    float ev[9], ssum = 0.f;
#pragma unroll
    for (int o = 0; o < 9; ++o) { ev[o] = expf(__fadd_rn(lg[o], -mx)); ssum += ev[o]; }
    float leta[9];
    size_t ebase = ((size_t)(b * 30 + c) * 49 + cell) * 9;
#pragma unroll
    for (int o = 0; o < 9; ++o) {
      float e = __fdiv_rn(ev[o], ssum);
      o_eta[ebase + o] = e;
      leta[o] = logf(e);
    }
    uint32_t fb = (uint32_t)ebase;
    float best1 = -3.4e38f, best2 = -3.4e38f, pooledv = 0.f;
    int z2 = 0;
#pragma unroll
    for (int t = 0; t < 9; ++t) {
      float v1 = __fadd_rn(leta[t], gumbel_draw(KPOOL0, KPOOL1, fb + t));
      bool t1 = v1 > best1; best1 = t1 ? v1 : best1; pooledv = t1 ? tile[t] : pooledv;
      float v2 = __fadd_rn(leta[t], gumbel_draw(KUNP0, KUNP1, fb + t));
      bool t2 = v2 > best2; best2 = t2 ? v2 : best2; z2 = t2 ? t : z2;
    }
    pooled[idx] = pooledv;
    ws_z[(size_t)b * 1470 + idx] = (unsigned char)z2;
  }

  float* wch = lds;
  float* c2s = lds + 7680;
  float* hs  = lds + 8960;
  for (int ch = 0; ch < 5; ++ch) {
    __syncthreads();
    for (int i = tid; i < 7680; i += 256) wch[i] = enc2_w[ch * 7680 + i];
    __syncthreads();
    int k2l = tid >> 4, pos = tid & 15;
    int uy = pos >> 2, ux = pos & 3;
    float acc = 0.f;
    for (int c = 0; c < 30; ++c) {
      const float* pc = &pooled[c * 49];
      const float* wr = &wch[(k2l * 30 + c) * 16];
#pragma unroll
      for (int dy = 0; dy < 4; ++dy)
#pragma unroll
        for (int dx = 0; dx < 4; ++dx)
          acc += pc[(uy + dy) * 7 + ux + dx] * wr[dy * 4 + dx];
    }
    c2s[(ch * 16 + k2l) * 16 + pos] = acc;
  }
  __syncthreads();

#pragma unroll
  for (int j = 0; j < 5; ++j) {
    int it = tid + j * 256;
    int k2 = it >> 4;
    float d = 0.f;
    const float* wr = &h_w[(size_t)it * 16];
#pragma unroll
    for (int i = 0; i < 16; ++i) d += c2s[k2 * 16 + i] * wr[i];
    hs[it] = tanh_xla(__fadd_rn(d, h_b[it]));
  }
  __syncthreads();

#pragma unroll
  for (int j = 0; j < 5; ++j) {
    int it = tid + j * 256;
    int k2 = it >> 4;
    float dm = 0.f, dl = 0.f;
    const float* wm = &mean_w[(size_t)it * 16];
    const float* wl = &lv_w[(size_t)it * 16];
#pragma unroll
    for (int i = 0; i < 16; ++i) {
      float hv = hs[k2 * 16 + i];
      dm += hv * wm[i];
      dl += hv * wl[i];
    }
    float mean = __fadd_rn(dm, mean_b[it]);
    float lv = __fadd_rn(dl, lv_b[it]);
    size_t gi = (size_t)b * 1280 + it;
    o_mean[gi] = mean;
    o_lv[gi] = lv;
    float stdv = expf(__fmul_rn(0.5f, lv));
    float z = normal_draw(KCODE0, KCODE1, (uint32_t)(b * 1280 + it));
    ws_s[gi] = __fadd_rn(mean, __fmul_rn(stdv, z));
  }
}

// ---------------------------------------------------------------------------
// k_expand: Wexp[k=1280][t=1472] from dec2_w.
// k = k2*16+iy*4+ix ; t = c*49+u*7+v ; val = dec2_w[k2,c,u-iy,v-ix] (valid) else 0
// ---------------------------------------------------------------------------
__global__ __launch_bounds__(256) void k_expand(const float* __restrict__ dec2_w,
                                                float* __restrict__ Wexp) {
  int idx = blockIdx.x * 256 + threadIdx.x;       // < 1280*1472
  int k = idx / 1472, t = idx - k * 1472;
  int k2 = k >> 4, iy = (k >> 2) & 3, ix = k & 3;
  int c = t / 49, cell = t - c * 49;
  int u = cell / 7, v = cell - u * 7;
  int du = u - iy, dv = v - ix;
  float val = 0.f;
  if (t < 1470 && (unsigned)du < 4u && (unsigned)dv < 4u)
    val = dec2_w[((k2 * 30 + c) << 4) + (du << 2) + dv];
  Wexp[idx] = val;
}

// ---------------------------------------------------------------------------
// k_gemm: S2[4096,1472] = A[4096,1280] x Wexp[1280,1472]
// BM=128, BN=64, BK=16, 256 threads, 8x4 micro-tile. k ascending (same
// summation order as the old convT loop, so s2 is numerically ~identical).
// ---------------------------------------------------------------------------
__global__ __launch_bounds__(256) void k_gemm(const float* __restrict__ A,
                                              const float* __restrict__ Bm,
                                              float* __restrict__ C) {
  __shared__ float As[16][132];   // [kk][mm], stride 132 keeps 16B alignment
  __shared__ float Bs[16][64];
  const int tid = threadIdx.x;
  const int n0 = blockIdx.x * 64;     // 23 tiles
  const int m0 = blockIdx.y * 128;    // 32 tiles
  const int tx = tid & 15, ty = tid >> 4;

  float acc[8][4];
#pragma unroll
  for (int i = 0; i < 8; ++i)
#pragma unroll
    for (int j = 0; j < 4; ++j) acc[i][j] = 0.f;

  // staging decomposition
  const int fa_r0 = tid >> 2, fa_c = (tid & 3) << 2;          // A: f=tid, f+256
  const int fb_k = tid >> 4, fb_c = (tid & 15) << 2;          // B: f=tid

  for (int k0 = 0; k0 < 1280; k0 += 16) {
    __syncthreads();
    float4 a0 = *(const float4*)&A[(size_t)(m0 + fa_r0) * 1280 + k0 + fa_c];
    float4 a1 = *(const float4*)&A[(size_t)(m0 + 64 + fa_r0) * 1280 + k0 + fa_c];
    float4 bv = *(const float4*)&Bm[(size_t)(k0 + fb_k) * 1472 + n0 + fb_c];
    As[fa_c + 0][fa_r0] = a0.x;  As[fa_c + 1][fa_r0] = a0.y;
    As[fa_c + 2][fa_r0] = a0.z;  As[fa_c + 3][fa_r0] = a0.w;
    As[fa_c + 0][64 + fa_r0] = a1.x;  As[fa_c + 1][64 + fa_r0] = a1.y;
    As[fa_c + 2][64 + fa_r0] = a1.z;  As[fa_c + 3][64 + fa_r0] = a1.w;
    *(float4*)&Bs[fb_k][fb_c] = bv;
    __syncthreads();

#pragma unroll
    for (int kk = 0; kk < 16; ++kk) {
      float4 av0 = *(const float4*)&As[kk][ty * 8];
      float4 av1 = *(const float4*)&As[kk][ty * 8 + 4];
      float4 bv0 = *(const float4*)&Bs[kk][tx * 4];
      float am[8] = {av0.x, av0.y, av0.z, av0.w, av1.x, av1.y, av1.z, av1.w};
      float bn[4] = {bv0.x, bv0.y, bv0.z, bv0.w};
#pragma unroll
      for (int i = 0; i < 8; ++i)
#pragma unroll
        for (int j = 0; j < 4; ++j) acc[i][j] = __fmaf_rn(am[i], bn[j], acc[i][j]);
    }
  }

#pragma unroll
  for (int i = 0; i < 8; ++i) {
    size_t row = (size_t)(m0 + ty * 8 + i);
    float4 o = make_float4(acc[i][0], acc[i][1], acc[i][2], acc[i][3]);
    *(float4*)&C[row * 1472 + n0 + tx * 4] = o;
  }
}

// ---------------------------------------------------------------------------
// k_unpool: scatter s2 tiles through zeta2 into x_acc (LDS f32 atomics),
// add diagonal noise, write x_rec. One block per batch.
// ---------------------------------------------------------------------------
__global__ __launch_bounds__(256) void k_unpool(
    const float* __restrict__ S2, const unsigned char* __restrict__ ws_z,
    const float* __restrict__ dec1_w, const float* __restrict__ alpha,
    float* __restrict__ o_xrec) {
  __shared__ float w1s[1920];
  __shared__ float xacc[784];
  const int b = blockIdx.x, tid = threadIdx.x;

  for (int i = tid; i < 1920; i += 256) w1s[i] = dec1_w[i];
  for (int i = tid; i < 784; i += 256) xacc[i] = 0.f;
  __syncthreads();

#pragma unroll
  for (int j = 0; j < 6; ++j) {
    int t = tid + j * 256;
    if (t < 1470) {
      int c = t / 49, cell = t - c * 49;
      int n = cell / 7, m = cell - n * 7;
      int z = ws_z[(size_t)b * 1470 + t];
      int p = z / 3, q = z - p * 3;
      int py = n * 3 + p, px = m * 3 + q;
      float val = S2[(size_t)b * 1472 + t];
      const float* wc = &w1s[c * 64];
#pragma unroll
      for (int r = 0; r < 8; ++r) {
        float4 wa = *(const float4*)&wc[r * 8];
        float4 wb = *(const float4*)&wc[r * 8 + 4];
        float* xrow = &xacc[(py + r) * 28 + px];
        atomicAdd(&xrow[0], val * wa.x);
        atomicAdd(&xrow[1], val * wa.y);
        atomicAdd(&xrow[2], val * wa.z);
        atomicAdd(&xrow[3], val * wa.w);
        atomicAdd(&xrow[4], val * wb.x);
        atomicAdd(&xrow[5], val * wb.y);
        atomicAdd(&xrow[6], val * wb.z);
        atomicAdd(&xrow[7], val * wb.w);
      }
    }
  }
  __syncthreads();

  float inva = __fdiv_rn(1.0f, alpha[0]);
  for (int pix = tid; pix < 784; pix += 256) {
    int y = pix / 28, xx = pix - y * 28;
    float a = xacc[pix];
    if (y == xx) {
      float zn = normal_draw(KNOIS0, KNOIS1, (uint32_t)(b * 784 + pix));
      a = __fadd_rn(a, __fmul_rn(inva, zn));
    }
    o_xrec[(size_t)b * 784 + pix] = a;
  }
}

// ---------------------------------------------------------------------------
extern "C" void kernel_launch(void* const* d_in, const int* in_sizes, int n_in,
                              void* d_out, int out_size, void* d_ws, size_t ws_size,
                              hipStream_t stream) {
  const float* x      = (const float*)d_in[0];
  const float* enc1_w = (const float*)d_in[1];
  const float* pw1    = (const float*)d_in[2];
  const float* pw2    = (const float*)d_in[3];
  const float* enc2_w = (const float*)d_in[4];
  const float* h_w    = (const float*)d_in[5];
  const float* h_b    = (const float*)d_in[6];
  const float* mean_w = (const float*)d_in[7];
  const float* mean_b = (const float*)d_in[8];
  const float* lv_w   = (const float*)d_in[9];
  const float* lv_b   = (const float*)d_in[10];
  const float* dec2_w = (const float*)d_in[11];
  const float* dec1_w = (const float*)d_in[12];
  const float* alpha  = (const float*)d_in[13];

  float* out = (float*)d_out;
  float* o_xrec = out;
  float* o_mean = out + OFF_MEAN;
  float* o_lv   = out + OFF_LV;
  float* o_eta  = out + OFF_ETA;

  // workspace layout (bytes):
  //   ws_s  : 0                .. 20,971,520   (4096x1280 f32)
  //   ws_z  : 20,971,520       .. 26,992,640   (4096x1470 u8)
  //   Wexp  : 26,992,640       .. 34,529,280   (1280x1472 f32)
  //   S2    : 34,529,280       .. 58,646,528   (4096x1472 f32)
  char* wsb = (char*)d_ws;
  float* ws_s = (float*)wsb;
  unsigned char* ws_z = (unsigned char*)(wsb + 20971520);
  float* Wexp = (float*)(wsb + 26992640);
  float* S2   = (float*)(wsb + 34529280);

  k_expand<<<dim3(7360), dim3(256), 0, stream>>>(dec2_w, Wexp);
  k_enc<<<dim3(4096), dim3(256), 0, stream>>>(
      x, enc1_w, pw1, pw2, enc2_w, h_w, h_b, mean_w, mean_b, lv_w, lv_b,
      o_mean, o_lv, o_eta, ws_s, ws_z);
  k_gemm<<<dim3(23, 32), dim3(256), 0, stream>>>(ws_s, Wexp, S2);
  k_unpool<<<dim3(4096), dim3(256), 0, stream>>>(S2, ws_z, dec1_w, alpha, o_xrec);
}